// Round 14
// baseline (110.731 us; speedup 1.0000x reference)
//
#include <hip/hip_runtime.h>
#include <stdint.h>

#define C_INN 512
#define C_OUTT 512
#define LL 4096
#define KDIM 1536   // C_IN*K

typedef __attribute__((ext_vector_type(8))) short bf16x8;
typedef __attribute__((ext_vector_type(4))) float f32x4;

static __device__ __forceinline__ uint16_t f2bf(float f) {
    union { float f; uint32_t u; } c; c.f = f;
    uint32_t u = c.u;
    uint32_t r = u + 0x7FFFu + ((u >> 16) & 1u);   // RNE
    return (uint16_t)(r >> 16);
}

static __device__ __forceinline__ void gload_lds16(const uint16_t* g, uint16_t* l) {
    __builtin_amdgcn_global_load_lds(
        (const __attribute__((address_space(1))) uint32_t*)g,
        (__attribute__((address_space(3))) uint32_t*)l, 16, 0, 0);
}

// ---------------- pass 1a: offset-conv partials (+ fused w_conv cast) ----------
__global__ __launch_bounds__(256) void k_off1(const float* __restrict__ x,
        const float* __restrict__ wo, float* __restrict__ part,
        const float* __restrict__ wc, uint16_t* __restrict__ Ab) {
    const int split = blockIdx.x;
    const int tile  = blockIdx.y;
    const int n     = blockIdx.z;
    const int tid = threadIdx.x;

    if (split >= 8) {                            // ---- convA path ----
        int blk = ((split - 8) * 16 + tile) * 8 + n;
        int i = (blk * 256 + tid) * 4;           // 768*256*4 = 786432 exact
        float4 v = *(const float4*)(wc + i);
        ushort4 o;
        o.x = f2bf(v.x); o.y = f2bf(v.y); o.z = f2bf(v.z); o.w = f2bf(v.w);
        *(ushort4*)(Ab + i) = o;
        return;
    }

    const int w = tid >> 6, lane = tid & 63;
    const int lo0 = tile * 256;
    const int ch0 = split * 64;

    __shared__ float4 wq[64][3];
    for (int i = tid; i < 576; i += 256) {
        int cl = i / 9, r = i - cl * 9;
        int k = r / 3, t = r - k * 3;
        ((float*)wq)[cl * 12 + r] = wo[(2 * k) * 1536 + (ch0 + cl) * 3 + t];
    }
    __syncthreads();

    float4 a0 = {0,0,0,0}, a1 = {0,0,0,0}, a2 = {0,0,0,0};
    const float* xn = x + ((size_t)n * C_INN + ch0 + w * 16) * LL + lo0;
    #pragma unroll 4
    for (int it = 0; it < 16; ++it) {
        const float* xp = xn + (size_t)it * LL;
        float4 v = *(const float4*)(xp + 4 * lane);
        float xl = xp[(lo0 > 0) ? -1 : 0];
        float xr = xp[(lo0 < 3840) ? 256 : 255];
        float lm = __shfl_up(v.w, 1, 64);
        lm = (lane == 0) ? ((lo0 > 0) ? xl : 0.f) : lm;
        float rp = __shfl_down(v.x, 1, 64);
        rp = (lane == 63) ? ((lo0 < 3840) ? xr : 0.f) : rp;
        int cl = w * 16 + it;
        float4 q0 = wq[cl][0], q1 = wq[cl][1], q2 = wq[cl][2];
        a0.x += q0.x * lm   + q0.y * v.x + q0.z * v.y;
        a0.y += q0.x * v.x  + q0.y * v.y + q0.z * v.z;
        a0.z += q0.x * v.y  + q0.y * v.z + q0.z * v.w;
        a0.w += q0.x * v.z  + q0.y * v.w + q0.z * rp;
        a1.x += q0.w * lm   + q1.x * v.x + q1.y * v.y;
        a1.y += q0.w * v.x  + q1.x * v.y + q1.y * v.z;
        a1.z += q0.w * v.y  + q1.x * v.z + q1.y * v.w;
        a1.w += q0.w * v.z  + q1.x * v.w + q1.y * rp;
        a2.x += q1.z * lm   + q1.w * v.x + q2.x * v.y;
        a2.y += q1.z * v.x  + q1.w * v.y + q2.x * v.z;
        a2.z += q1.z * v.y  + q1.w * v.z + q2.x * v.w;
        a2.w += q1.z * v.z  + q1.w * v.w + q2.x * rp;
    }

    __shared__ float4 red[4][3][64];
    red[w][0][lane] = a0; red[w][1][lane] = a1; red[w][2][lane] = a2;
    __syncthreads();
    if (tid < 192) {
        int k = tid >> 6, l = tid & 63;
        float4 r0 = red[0][k][l], r1 = red[1][k][l], r2 = red[2][k][l], r3 = red[3][k][l];
        float4 s;
        s.x = r0.x + r1.x + r2.x + r3.x;
        s.y = r0.y + r1.y + r2.y + r3.y;
        s.z = r0.z + r1.z + r2.z + r3.z;
        s.w = r0.w + r1.w + r2.w + r3.w;
        float4* p4 = (float4*)part;
        p4[(size_t)(((n * 16 + tile) * 8 + split)) * 192 + k * 64 + l] = s;
    }
}

// ---------------- pass 1b: reduce partials -> (li, alpha) ----------------
__global__ __launch_bounds__(256) void k_off2(const float* __restrict__ part,
        const float* __restrict__ bo, float2* __restrict__ liA) {
    const int b = blockIdx.x;
    const int n = b >> 4, tile = b & 15;
    const int tid = threadIdx.x;
    const int lo = tile * 256 + tid;
    #pragma unroll
    for (int k = 0; k < 3; ++k) {
        float s = 0.f;
        #pragma unroll
        for (int sp = 0; sp < 8; ++sp)
            s += part[(size_t)(b * 8 + sp) * 768 + k * 256 + tid];
        s += bo[2 * k];
        float g = fminf(fmaxf((float)(lo + 1) + s, 0.f), 4097.f);
        float lif = floorf(g);
        liA[((n * 3 + k) * 8 + (lo & 7)) * 512 + (lo >> 3)] = make_float2(lif, g - lif);
    }
}

// ---------------- pass 2: build Bt[(nl*4096+l)][k*512+j] bf16 ----------------
__global__ __launch_bounds__(512) void k_build(const float* __restrict__ x,
        const float2* __restrict__ liA, uint16_t* __restrict__ Bt, int n0) {
    const int c0 = blockIdx.x * 4;
    const int nl = blockIdx.y;
    const int n  = n0 + nl;
    const int tid = threadIdx.x;
    __shared__ float xs[4][4232];               // skewed s(p)=p+(p>>5); slot 4228 = 0
    #pragma unroll
    for (int c4 = 0; c4 < 4; ++c4) {
        const float* xr = x + ((size_t)n * C_INN + c0 + c4) * LL + tid * 8;
        float4 v0 = *(const float4*)xr;
        float4 v1 = *(const float4*)(xr + 4);
        int p = tid * 8;
        int sb = p + (p >> 5);
        float* xsp = xs[c4];
        xsp[sb + 0] = v0.x; xsp[sb + 1] = v0.y; xsp[sb + 2] = v0.z; xsp[sb + 3] = v0.w;
        xsp[sb + 4] = v1.x; xsp[sb + 5] = v1.y; xsp[sb + 6] = v1.z; xsp[sb + 7] = v1.w;
        if (tid == 0) xsp[4228] = 0.f;
    }
    __syncthreads();
    const int q = tid >> 6, lane = tid & 63;
    uint32_t* outp0 = (uint32_t*)(Bt + (size_t)(nl * LL + q * 512 + c0) * KDIM);
    #pragma unroll
    for (int k = 0; k < 3; ++k) {
        const float2* lp = liA + ((size_t)((n * 3 + k) * 8 + q)) * 512;
        #pragma unroll
        for (int jc = 0; jc < 4; ++jc) {
            float4 la = *(const float4*)(lp + jc * 128 + 2 * lane);  // li0,a0,li1,a1
            int li0 = (int)la.x; float a0 = la.y;
            int li1 = (int)la.z; float a1 = la.w;
            int l0m = li0 - 1, l1m = li1 - 1;
            int iL0 = ((unsigned)l0m < 4096u) ? (l0m + (l0m >> 5)) : 4228;
            int iR0 = ((unsigned)li0 < 4096u) ? (li0 + (li0 >> 5)) : 4228;
            int iL1 = ((unsigned)l1m < 4096u) ? (l1m + (l1m >> 5)) : 4228;
            int iR1 = ((unsigned)li1 < 4096u) ? (li1 + (li1 >> 5)) : 4228;
            #pragma unroll
            for (int c4 = 0; c4 < 4; ++c4) {
                const float* xsp = xs[c4];
                float xl0 = xsp[iL0], xr0 = xsp[iR0];
                float xl1 = xsp[iL1], xr1 = xsp[iR1];
                float v0 = xl0 + a0 * (xr0 - xl0);
                float v1 = xl1 + a1 * (xr1 - xl1);
                uint32_t pk;
                asm("v_cvt_pk_bf16_f32 %0, %1, %2" : "=v"(pk) : "v"(v0), "v"(v1));
                outp0[(size_t)c4 * KDIM / 2 + k * 256 + jc * 64 + lane] = pk;
            }
        }
    }
}

// ---------------- pass 3: GEMM, 256x256 tile, BK=64, 8-phase (r13 + nt stores) -----
// Only change vs r13: epilogue stores are non-temporal (out has zero reuse;
// bypassing cache retention keeps Bt resident in L3 -> FETCH_SIZE should drop
// from ~56 MB to ~5-15 MB).
#define SBAR() do { asm volatile("" ::: "memory"); __builtin_amdgcn_s_barrier(); asm volatile("" ::: "memory"); } while (0)
#define VMC(n) asm volatile("s_waitcnt vmcnt(" #n ")" ::: "memory")

__global__ __launch_bounds__(512, 2) void k_gemm(const uint16_t* __restrict__ Ab,
        const uint16_t* __restrict__ Bt, const float* __restrict__ bias,
        float* __restrict__ out, int n0) {
    const int bid = blockIdx.x;
    const int cpx = gridDim.x >> 3;
    const int swz = (bid & 7) * cpx + (bid >> 3);
    const int mt = swz & 1;
    const int nt = swz >> 1;
    const int row0 = mt * 256;
    const int col0 = nt * 256;
    const int tid = threadIdx.x;
    const int wv = tid >> 6, lane = tid & 63;
    const int wr = wv >> 2, wc = wv & 3;
    const int r16 = lane & 15, kg = lane >> 4;

    __shared__ uint16_t As[2][16384];
    __shared__ uint16_t Bs[2][16384];

    f32x4 acc[8][4] = {};

    float4 bpre[8];
    #pragma unroll
    for (int m = 0; m < 8; ++m)
        bpre[m] = *(const float4*)(bias + row0 + wr * 128 + m * 16 + kg * 4);

    const int sr  = tid >> 3;
    const int skc = (tid & 7) ^ (sr & 7);
    const uint16_t* Asrc = Ab + (size_t)(row0 + sr) * KDIM + skc * 8;
    const uint16_t* Bsrc = Bt + (size_t)(col0 + sr) * KDIM + skc * 8;

    const int xorw = (r16 & 7) * 8;
    const int kko0 = (kg * 8) ^ xorw;
    const int kko1 = (32 + kg * 8) ^ xorw;

    auto stageA = [&](int slot, int half, int kt) {
        const uint16_t* g = Asrc + (size_t)half * 128 * KDIM + kt * 64;
        uint16_t* l = &As[slot][half * 8192 + tid * 8];
        gload_lds16(g, l);
        gload_lds16(g + (size_t)64 * KDIM, l + 4096);
    };
    auto stageB = [&](int slot, int half, int kt) {
        const uint16_t* g = Bsrc + (size_t)half * 128 * KDIM + kt * 64;
        uint16_t* l = &Bs[slot][half * 8192 + tid * 8];
        gload_lds16(g, l);
        gload_lds16(g + (size_t)64 * KDIM, l + 4096);
    };

    bf16x8 af[2][2], bfr[4][2];

#define LDAQ(s, q) do { \
    af[0][0] = *(const bf16x8*)(&As[s][(wr*128 + (q)*32      + r16) * 64 + kko0]); \
    af[0][1] = *(const bf16x8*)(&As[s][(wr*128 + (q)*32      + r16) * 64 + kko1]); \
    af[1][0] = *(const bf16x8*)(&As[s][(wr*128 + (q)*32 + 16 + r16) * 64 + kko0]); \
    af[1][1] = *(const bf16x8*)(&As[s][(wr*128 + (q)*32 + 16 + r16) * 64 + kko1]); \
} while (0)

#define LDBALL(s) do { \
    _Pragma("unroll") \
    for (int nn = 0; nn < 4; ++nn) { \
        bfr[nn][0] = *(const bf16x8*)(&Bs[s][(wc*64 + nn*16 + r16) * 64 + kko0]); \
        bfr[nn][1] = *(const bf16x8*)(&Bs[s][(wc*64 + nn*16 + r16) * 64 + kko1]); \
    } \
} while (0)

#define MQ(q) do { \
    __builtin_amdgcn_s_setprio(1); \
    _Pragma("unroll") \
    for (int mi = 0; mi < 2; ++mi) { \
        _Pragma("unroll") \
        for (int nn = 0; nn < 4; ++nn) { \
            acc[(q)*2+mi][nn] = __builtin_amdgcn_mfma_f32_16x16x32_bf16(af[mi][0], bfr[nn][0], acc[(q)*2+mi][nn], 0, 0, 0); \
            acc[(q)*2+mi][nn] = __builtin_amdgcn_mfma_f32_16x16x32_bf16(af[mi][1], bfr[nn][1], acc[(q)*2+mi][nn], 0, 0, 0); \
        } \
    } \
    __builtin_amdgcn_s_setprio(0); \
} while (0)

    stageA(0, 0, 0); stageA(0, 1, 0);
    stageB(0, 0, 0); stageB(0, 1, 0);
    stageB(1, 0, 1); stageB(1, 1, 1);
    VMC(0);
    SBAR();

    for (int j = 0; j < 11; ++j) {               // K-tiles 0..21; 22,23 peeled below
        const int kt1  = 2 * j + 1;
        const int ktn0 = 2 * j + 2;
        const int ktn1 = 2 * j + 3;
        LDBALL(0); LDAQ(0, 0); stageA(1, 0, kt1);
        SBAR(); MQ(0);
        LDAQ(0, 1); stageA(1, 1, kt1);
        SBAR(); MQ(1);
        LDAQ(0, 2); stageB(0, 0, ktn0);
        SBAR(); MQ(2);
        LDAQ(0, 3); stageB(0, 1, ktn0);
        SBAR(); MQ(3); VMC(4); SBAR();
        LDBALL(1); LDAQ(1, 0); stageA(0, 0, ktn0);
        SBAR(); MQ(0);
        LDAQ(1, 1); stageA(0, 1, ktn0);
        SBAR(); MQ(1);
        LDAQ(1, 2); stageB(1, 0, ktn1);
        SBAR(); MQ(2);
        LDAQ(1, 3); stageB(1, 1, ktn1);
        SBAR(); MQ(3); VMC(4); SBAR();
    }

    // peeled tail: K-tiles 22 (slot 0) and 23 (slot 1)
    LDBALL(0); LDAQ(0, 0); stageA(1, 0, 23);
    SBAR(); MQ(0);
    LDAQ(0, 1); stageA(1, 1, 23);
    SBAR(); MQ(1);
    LDAQ(0, 2);
    SBAR(); MQ(2);
    LDAQ(0, 3);
    SBAR(); MQ(3); VMC(0); SBAR();
    LDBALL(1); LDAQ(1, 0);
    SBAR(); MQ(0);
    LDAQ(1, 1);
    SBAR(); MQ(1);
    LDAQ(1, 2);
    SBAR(); MQ(2);
    LDAQ(1, 3);
    SBAR(); MQ(3);

    const int rb = col0 + wc * 64;
    #pragma unroll
    for (int m = 0; m < 8; ++m) {
        #pragma unroll
        for (int e = 0; e < 4; ++e) {
            int o = row0 + wr * 128 + m * 16 + kg * 4 + e;
            float bv = ((const float*)&bpre[m])[e];
            #pragma unroll
            for (int nn = 0; nn < 4; ++nn) {
                int rc = rb + nn * 16 + r16;
                int nli = rc >> 12;
                int lpos = rc & 4095;
                __builtin_nontemporal_store(acc[m][nn][e] + bv,
                    &out[((size_t)(n0 + nli) * C_OUTT + o) * LL + lpos]);
            }
        }
    }
#undef LDAQ
#undef LDBALL
#undef MQ
}

extern "C" void kernel_launch(void* const* d_in, const int* in_sizes, int n_in,
                              void* d_out, int out_size, void* d_ws, size_t ws_size,
                              hipStream_t stream) {
    const float* x  = (const float*)d_in[0];
    const float* wo = (const float*)d_in[1];
    const float* bo = (const float*)d_in[2];
    const float* wc = (const float*)d_in[3];
    const float* bc = (const float*)d_in[4];
    float* out = (float*)d_out;

    char* ws = (char*)d_ws;
    uint16_t* Ab   = (uint16_t*)ws;                      // 1572864 B
    float2*   liA  = (float2*)(ws + 1572864);            // 786432 B
    float*    part = (float*)(ws + 2359296);             // 3145728 B
    uint16_t* Bt   = (uint16_t*)(ws + 5505024);          // nc * 12582912 B
    const size_t fixed = 5505024;
    int nc = 8;
    while (nc > 1 && fixed + (size_t)nc * 12582912ull > ws_size) nc >>= 1;

    k_off1<<<dim3(14, 16, 8), 256, 0, stream>>>(x, wo, part, wc, Ab);
    k_off2<<<128, 256, 0, stream>>>(part, bo, liA);
    for (int n0 = 0; n0 < 8; n0 += nc) {
        k_build<<<dim3(128, nc), 512, 0, stream>>>(x, liA, Bt, n0);
        k_gemm<<<2 * nc * 16, 512, 0, stream>>>(Ab, Bt, bc, out, n0);
    }
}

// Round 15
// 103.267 us; speedup vs baseline: 1.0723x; 1.0723x over previous
//
#include <hip/hip_runtime.h>
#include <stdint.h>

#define C_INN 512
#define C_OUTT 512
#define LL 4096
#define KDIM 1536   // C_IN*K

typedef __attribute__((ext_vector_type(8))) short bf16x8;
typedef __attribute__((ext_vector_type(4))) float f32x4;

static __device__ __forceinline__ uint16_t f2bf(float f) {
    union { float f; uint32_t u; } c; c.f = f;
    uint32_t u = c.u;
    uint32_t r = u + 0x7FFFu + ((u >> 16) & 1u);   // RNE
    return (uint16_t)(r >> 16);
}

static __device__ __forceinline__ void gload_lds16(const uint16_t* g, uint16_t* l) {
    __builtin_amdgcn_global_load_lds(
        (const __attribute__((address_space(1))) uint32_t*)g,
        (__attribute__((address_space(3))) uint32_t*)l, 16, 0, 0);
}

// ---------------- pass 1a: offset-conv partials (+ fused w_conv cast) ----------
__global__ __launch_bounds__(256) void k_off1(const float* __restrict__ x,
        const float* __restrict__ wo, float* __restrict__ part,
        const float* __restrict__ wc, uint16_t* __restrict__ Ab) {
    const int split = blockIdx.x;
    const int tile  = blockIdx.y;
    const int n     = blockIdx.z;
    const int tid = threadIdx.x;

    if (split >= 8) {                            // ---- convA path ----
        int blk = ((split - 8) * 16 + tile) * 8 + n;
        int i = (blk * 256 + tid) * 4;           // 768*256*4 = 786432 exact
        float4 v = *(const float4*)(wc + i);
        ushort4 o;
        o.x = f2bf(v.x); o.y = f2bf(v.y); o.z = f2bf(v.z); o.w = f2bf(v.w);
        *(ushort4*)(Ab + i) = o;
        return;
    }

    const int w = tid >> 6, lane = tid & 63;
    const int lo0 = tile * 256;
    const int ch0 = split * 64;

    __shared__ float4 wq[64][3];
    for (int i = tid; i < 576; i += 256) {
        int cl = i / 9, r = i - cl * 9;
        int k = r / 3, t = r - k * 3;
        ((float*)wq)[cl * 12 + r] = wo[(2 * k) * 1536 + (ch0 + cl) * 3 + t];
    }
    __syncthreads();

    float4 a0 = {0,0,0,0}, a1 = {0,0,0,0}, a2 = {0,0,0,0};
    const float* xn = x + ((size_t)n * C_INN + ch0 + w * 16) * LL + lo0;
    #pragma unroll 4
    for (int it = 0; it < 16; ++it) {
        const float* xp = xn + (size_t)it * LL;
        float4 v = *(const float4*)(xp + 4 * lane);
        float xl = xp[(lo0 > 0) ? -1 : 0];
        float xr = xp[(lo0 < 3840) ? 256 : 255];
        float lm = __shfl_up(v.w, 1, 64);
        lm = (lane == 0) ? ((lo0 > 0) ? xl : 0.f) : lm;
        float rp = __shfl_down(v.x, 1, 64);
        rp = (lane == 63) ? ((lo0 < 3840) ? xr : 0.f) : rp;
        int cl = w * 16 + it;
        float4 q0 = wq[cl][0], q1 = wq[cl][1], q2 = wq[cl][2];
        a0.x += q0.x * lm   + q0.y * v.x + q0.z * v.y;
        a0.y += q0.x * v.x  + q0.y * v.y + q0.z * v.z;
        a0.z += q0.x * v.y  + q0.y * v.z + q0.z * v.w;
        a0.w += q0.x * v.z  + q0.y * v.w + q0.z * rp;
        a1.x += q0.w * lm   + q1.x * v.x + q1.y * v.y;
        a1.y += q0.w * v.x  + q1.x * v.y + q1.y * v.z;
        a1.z += q0.w * v.y  + q1.x * v.z + q1.y * v.w;
        a1.w += q0.w * v.z  + q1.x * v.w + q1.y * rp;
        a2.x += q1.z * lm   + q1.w * v.x + q2.x * v.y;
        a2.y += q1.z * v.x  + q1.w * v.y + q2.x * v.z;
        a2.z += q1.z * v.y  + q1.w * v.z + q2.x * v.w;
        a2.w += q1.z * v.z  + q1.w * v.w + q2.x * rp;
    }

    __shared__ float4 red[4][3][64];
    red[w][0][lane] = a0; red[w][1][lane] = a1; red[w][2][lane] = a2;
    __syncthreads();
    if (tid < 192) {
        int k = tid >> 6, l = tid & 63;
        float4 r0 = red[0][k][l], r1 = red[1][k][l], r2 = red[2][k][l], r3 = red[3][k][l];
        float4 s;
        s.x = r0.x + r1.x + r2.x + r3.x;
        s.y = r0.y + r1.y + r2.y + r3.y;
        s.z = r0.z + r1.z + r2.z + r3.z;
        s.w = r0.w + r1.w + r2.w + r3.w;
        float4* p4 = (float4*)part;
        p4[(size_t)(((n * 16 + tile) * 8 + split)) * 192 + k * 64 + l] = s;
    }
}

// ---------------- pass 1b: reduce partials -> (li, alpha) ----------------
__global__ __launch_bounds__(256) void k_off2(const float* __restrict__ part,
        const float* __restrict__ bo, float2* __restrict__ liA) {
    const int b = blockIdx.x;
    const int n = b >> 4, tile = b & 15;
    const int tid = threadIdx.x;
    const int lo = tile * 256 + tid;
    #pragma unroll
    for (int k = 0; k < 3; ++k) {
        float s = 0.f;
        #pragma unroll
        for (int sp = 0; sp < 8; ++sp)
            s += part[(size_t)(b * 8 + sp) * 768 + k * 256 + tid];
        s += bo[2 * k];
        float g = fminf(fmaxf((float)(lo + 1) + s, 0.f), 4097.f);
        float lif = floorf(g);
        liA[((n * 3 + k) * 8 + (lo & 7)) * 512 + (lo >> 3)] = make_float2(lif, g - lif);
    }
}

// ---------------- pass 2: build Bt[(nl*4096+l)][k*512+j] bf16 ----------------
__global__ __launch_bounds__(512) void k_build(const float* __restrict__ x,
        const float2* __restrict__ liA, uint16_t* __restrict__ Bt, int n0) {
    const int c0 = blockIdx.x * 4;
    const int nl = blockIdx.y;
    const int n  = n0 + nl;
    const int tid = threadIdx.x;
    __shared__ float xs[4][4232];               // skewed s(p)=p+(p>>5); slot 4228 = 0
    #pragma unroll
    for (int c4 = 0; c4 < 4; ++c4) {
        const float* xr = x + ((size_t)n * C_INN + c0 + c4) * LL + tid * 8;
        float4 v0 = *(const float4*)xr;
        float4 v1 = *(const float4*)(xr + 4);
        int p = tid * 8;
        int sb = p + (p >> 5);
        float* xsp = xs[c4];
        xsp[sb + 0] = v0.x; xsp[sb + 1] = v0.y; xsp[sb + 2] = v0.z; xsp[sb + 3] = v0.w;
        xsp[sb + 4] = v1.x; xsp[sb + 5] = v1.y; xsp[sb + 6] = v1.z; xsp[sb + 7] = v1.w;
        if (tid == 0) xsp[4228] = 0.f;
    }
    __syncthreads();
    const int q = tid >> 6, lane = tid & 63;
    uint32_t* outp0 = (uint32_t*)(Bt + (size_t)(nl * LL + q * 512 + c0) * KDIM);
    #pragma unroll
    for (int k = 0; k < 3; ++k) {
        const float2* lp = liA + ((size_t)((n * 3 + k) * 8 + q)) * 512;
        #pragma unroll
        for (int jc = 0; jc < 4; ++jc) {
            float4 la = *(const float4*)(lp + jc * 128 + 2 * lane);  // li0,a0,li1,a1
            int li0 = (int)la.x; float a0 = la.y;
            int li1 = (int)la.z; float a1 = la.w;
            int l0m = li0 - 1, l1m = li1 - 1;
            int iL0 = ((unsigned)l0m < 4096u) ? (l0m + (l0m >> 5)) : 4228;
            int iR0 = ((unsigned)li0 < 4096u) ? (li0 + (li0 >> 5)) : 4228;
            int iL1 = ((unsigned)l1m < 4096u) ? (l1m + (l1m >> 5)) : 4228;
            int iR1 = ((unsigned)li1 < 4096u) ? (li1 + (li1 >> 5)) : 4228;
            #pragma unroll
            for (int c4 = 0; c4 < 4; ++c4) {
                const float* xsp = xs[c4];
                float xl0 = xsp[iL0], xr0 = xsp[iR0];
                float xl1 = xsp[iL1], xr1 = xsp[iR1];
                float v0 = xl0 + a0 * (xr0 - xl0);
                float v1 = xl1 + a1 * (xr1 - xl1);
                uint32_t pk;
                asm("v_cvt_pk_bf16_f32 %0, %1, %2" : "=v"(pk) : "v"(v0), "v"(v1));
                outp0[(size_t)c4 * KDIM / 2 + k * 256 + jc * 64 + lane] = pk;
            }
        }
    }
}

// ---------------- pass 3: GEMM, 256x256 tile, BK=64, 8-phase (r13, best) ----------
// 512 threads, 8 waves (2M x 4N), thinned barriers, XOR swizzle, peeled tail,
// bias preload, plain stores. Measured best total: 103.5 us.
#define SBAR() do { asm volatile("" ::: "memory"); __builtin_amdgcn_s_barrier(); asm volatile("" ::: "memory"); } while (0)
#define VMC(n) asm volatile("s_waitcnt vmcnt(" #n ")" ::: "memory")

__global__ __launch_bounds__(512, 2) void k_gemm(const uint16_t* __restrict__ Ab,
        const uint16_t* __restrict__ Bt, const float* __restrict__ bias,
        float* __restrict__ out, int n0) {
    const int bid = blockIdx.x;
    const int cpx = gridDim.x >> 3;
    const int swz = (bid & 7) * cpx + (bid >> 3);
    const int mt = swz & 1;
    const int nt = swz >> 1;
    const int row0 = mt * 256;
    const int col0 = nt * 256;
    const int tid = threadIdx.x;
    const int wv = tid >> 6, lane = tid & 63;
    const int wr = wv >> 2, wc = wv & 3;
    const int r16 = lane & 15, kg = lane >> 4;

    __shared__ uint16_t As[2][16384];
    __shared__ uint16_t Bs[2][16384];

    f32x4 acc[8][4] = {};

    float4 bpre[8];
    #pragma unroll
    for (int m = 0; m < 8; ++m)
        bpre[m] = *(const float4*)(bias + row0 + wr * 128 + m * 16 + kg * 4);

    const int sr  = tid >> 3;
    const int skc = (tid & 7) ^ (sr & 7);
    const uint16_t* Asrc = Ab + (size_t)(row0 + sr) * KDIM + skc * 8;
    const uint16_t* Bsrc = Bt + (size_t)(col0 + sr) * KDIM + skc * 8;

    const int xorw = (r16 & 7) * 8;
    const int kko0 = (kg * 8) ^ xorw;
    const int kko1 = (32 + kg * 8) ^ xorw;

    auto stageA = [&](int slot, int half, int kt) {
        const uint16_t* g = Asrc + (size_t)half * 128 * KDIM + kt * 64;
        uint16_t* l = &As[slot][half * 8192 + tid * 8];
        gload_lds16(g, l);
        gload_lds16(g + (size_t)64 * KDIM, l + 4096);
    };
    auto stageB = [&](int slot, int half, int kt) {
        const uint16_t* g = Bsrc + (size_t)half * 128 * KDIM + kt * 64;
        uint16_t* l = &Bs[slot][half * 8192 + tid * 8];
        gload_lds16(g, l);
        gload_lds16(g + (size_t)64 * KDIM, l + 4096);
    };

    bf16x8 af[2][2], bfr[4][2];

#define LDAQ(s, q) do { \
    af[0][0] = *(const bf16x8*)(&As[s][(wr*128 + (q)*32      + r16) * 64 + kko0]); \
    af[0][1] = *(const bf16x8*)(&As[s][(wr*128 + (q)*32      + r16) * 64 + kko1]); \
    af[1][0] = *(const bf16x8*)(&As[s][(wr*128 + (q)*32 + 16 + r16) * 64 + kko0]); \
    af[1][1] = *(const bf16x8*)(&As[s][(wr*128 + (q)*32 + 16 + r16) * 64 + kko1]); \
} while (0)

#define LDBALL(s) do { \
    _Pragma("unroll") \
    for (int nn = 0; nn < 4; ++nn) { \
        bfr[nn][0] = *(const bf16x8*)(&Bs[s][(wc*64 + nn*16 + r16) * 64 + kko0]); \
        bfr[nn][1] = *(const bf16x8*)(&Bs[s][(wc*64 + nn*16 + r16) * 64 + kko1]); \
    } \
} while (0)

#define MQ(q) do { \
    __builtin_amdgcn_s_setprio(1); \
    _Pragma("unroll") \
    for (int mi = 0; mi < 2; ++mi) { \
        _Pragma("unroll") \
        for (int nn = 0; nn < 4; ++nn) { \
            acc[(q)*2+mi][nn] = __builtin_amdgcn_mfma_f32_16x16x32_bf16(af[mi][0], bfr[nn][0], acc[(q)*2+mi][nn], 0, 0, 0); \
            acc[(q)*2+mi][nn] = __builtin_amdgcn_mfma_f32_16x16x32_bf16(af[mi][1], bfr[nn][1], acc[(q)*2+mi][nn], 0, 0, 0); \
        } \
    } \
    __builtin_amdgcn_s_setprio(0); \
} while (0)

    stageA(0, 0, 0); stageA(0, 1, 0);
    stageB(0, 0, 0); stageB(0, 1, 0);
    stageB(1, 0, 1); stageB(1, 1, 1);
    VMC(0);
    SBAR();

    for (int j = 0; j < 11; ++j) {               // K-tiles 0..21; 22,23 peeled below
        const int kt1  = 2 * j + 1;
        const int ktn0 = 2 * j + 2;
        const int ktn1 = 2 * j + 3;
        LDBALL(0); LDAQ(0, 0); stageA(1, 0, kt1);
        SBAR(); MQ(0);
        LDAQ(0, 1); stageA(1, 1, kt1);
        SBAR(); MQ(1);
        LDAQ(0, 2); stageB(0, 0, ktn0);
        SBAR(); MQ(2);
        LDAQ(0, 3); stageB(0, 1, ktn0);
        SBAR(); MQ(3); VMC(4); SBAR();
        LDBALL(1); LDAQ(1, 0); stageA(0, 0, ktn0);
        SBAR(); MQ(0);
        LDAQ(1, 1); stageA(0, 1, ktn0);
        SBAR(); MQ(1);
        LDAQ(1, 2); stageB(1, 0, ktn1);
        SBAR(); MQ(2);
        LDAQ(1, 3); stageB(1, 1, ktn1);
        SBAR(); MQ(3); VMC(4); SBAR();
    }

    // peeled tail: K-tiles 22 (slot 0) and 23 (slot 1)
    LDBALL(0); LDAQ(0, 0); stageA(1, 0, 23);
    SBAR(); MQ(0);
    LDAQ(0, 1); stageA(1, 1, 23);
    SBAR(); MQ(1);
    LDAQ(0, 2);
    SBAR(); MQ(2);
    LDAQ(0, 3);
    SBAR(); MQ(3); VMC(0); SBAR();
    LDBALL(1); LDAQ(1, 0);
    SBAR(); MQ(0);
    LDAQ(1, 1);
    SBAR(); MQ(1);
    LDAQ(1, 2);
    SBAR(); MQ(2);
    LDAQ(1, 3);
    SBAR(); MQ(3);

    const int rb = col0 + wc * 64;
    #pragma unroll
    for (int m = 0; m < 8; ++m) {
        #pragma unroll
        for (int e = 0; e < 4; ++e) {
            int o = row0 + wr * 128 + m * 16 + kg * 4 + e;
            float bv = ((const float*)&bpre[m])[e];
            #pragma unroll
            for (int nn = 0; nn < 4; ++nn) {
                int rc = rb + nn * 16 + r16;
                int nli = rc >> 12;
                int lpos = rc & 4095;
                out[((size_t)(n0 + nli) * C_OUTT + o) * LL + lpos] = acc[m][nn][e] + bv;
            }
        }
    }
#undef LDAQ
#undef LDBALL
#undef MQ
}

extern "C" void kernel_launch(void* const* d_in, const int* in_sizes, int n_in,
                              void* d_out, int out_size, void* d_ws, size_t ws_size,
                              hipStream_t stream) {
    const float* x  = (const float*)d_in[0];
    const float* wo = (const float*)d_in[1];
    const float* bo = (const float*)d_in[2];
    const float* wc = (const float*)d_in[3];
    const float* bc = (const float*)d_in[4];
    float* out = (float*)d_out;

    char* ws = (char*)d_ws;
    uint16_t* Ab   = (uint16_t*)ws;                      // 1572864 B
    float2*   liA  = (float2*)(ws + 1572864);            // 786432 B
    float*    part = (float*)(ws + 2359296);             // 3145728 B
    uint16_t* Bt   = (uint16_t*)(ws + 5505024);          // nc * 12582912 B
    const size_t fixed = 5505024;
    int nc = 8;
    while (nc > 1 && fixed + (size_t)nc * 12582912ull > ws_size) nc >>= 1;

    k_off1<<<dim3(14, 16, 8), 256, 0, stream>>>(x, wo, part, wc, Ab);
    k_off2<<<128, 256, 0, stream>>>(part, bo, liA);
    for (int n0 = 0; n0 < 8; n0 += nc) {
        k_build<<<dim3(128, nc), 512, 0, stream>>>(x, liA, Bt, n0);
        k_gemm<<<2 * nc * 16, 512, 0, stream>>>(Ab, Bt, bc, out, n0);
    }
}